// Round 5
// baseline (849.785 us; speedup 1.0000x reference)
//
#include <hip/hip_runtime.h>
#include <hip/hip_bf16.h>
#include <cstdint>

#define B_ 4
#define SQ_ 128
#define SKV_ 8192
#define H_ 32
#define D_ 128
#define KT 64

typedef __bf16 bf16x8 __attribute__((ext_vector_type(8)));
typedef float f32x4 __attribute__((ext_vector_type(4)));

union U4B8 { uint4 u; bf16x8 v; };

__device__ inline unsigned f2b_pack(float a, float b){
  unsigned ua = __float_as_uint(a); ua = (ua + 0x7FFFu + ((ua >> 16) & 1u)) >> 16;
  unsigned ub = __float_as_uint(b); ub = (ub + 0x7FFFu + ((ub >> 16) & 1u)) >> 16;
  return (ua & 0xFFFFu) | (ub << 16);
}
__device__ inline unsigned short f2b1(float a){
  unsigned ua = __float_as_uint(a);
  return (unsigned short)((ua + 0x7FFFu + ((ua >> 16) & 1u)) >> 16);
}

// Split-KV attention. Block = 256 threads = 4 waves; each wave owns 32 Q rows.
// LDS = 32 KB: K [64][128]bf16 (16 KB) + V^T [128][64]bf16 (16 KB); the P
// buffer (4 KB/wave) is OVERLAID on the K region (safe: P is written only
// after a barrier that follows the last K read of the tile). 32 KB x 4 blocks
// = 128 KB LDS/CU; VGPR<=128 -> 16 waves/CU -> grid 1024 fully resident.
__global__ __launch_bounds__(256, 4) void mha_split_kernel(
    const float* __restrict__ q, const float* __restrict__ k, const float* __restrict__ v,
    float* __restrict__ Ubase, float* __restrict__ Lbase, float* __restrict__ outp, int nsplit)
{
  __shared__ char smem[32 * 1024] __attribute__((aligned(16)));
  char* Klds = smem;                 // [64][128] bf16, row 256B, swz ^((key&7)<<4)
  char* Vlds = smem + 16 * 1024;     // V^T [128][64] bf16, row 128B, swz ^(((d^(d>>2))&7)<<4)
  char* Plds = smem + (threadIdx.x >> 6) * 4096; // per-wave [32][64] bf16 OVERLAID on K region

  const int tid = threadIdx.x;
  const int w = tid >> 6;
  const int l = tid & 63;
  const int g = l >> 4;      // 16-lane group 0..3
  const int c = l & 15;      // lane within group
  const int bh = blockIdx.x;
  const int split = blockIdx.y;
  const int b = bh >> 5, h = bh & 31;
  const int kps = SKV_ / nsplit;
  const int kv0 = split * kps;
  const int nt = kps / KT;

  const float qscale = 0.08838834764831845f * 1.4426950408889634f; // 1/sqrt(128) * log2(e)

  // ---- Q fragments in registers (A-operand layout: m = c, k = ks*32 + g*8 + j)
  bf16x8 qf[2][4];
  {
    const float* qp = q + (((size_t)b * SQ_) * H_ + h) * D_;
#pragma unroll
    for (int mi = 0; mi < 2; ++mi) {
      int qrow = w * 32 + mi * 16 + c;
      const float* qr = qp + (size_t)qrow * H_ * D_;
#pragma unroll
      for (int ks = 0; ks < 4; ++ks) {
        int d0 = ks * 32 + g * 8;
        float4 x = *(const float4*)(qr + d0);
        float4 y = *(const float4*)(qr + d0 + 4);
        U4B8 t;
        t.u.x = f2b_pack(x.x * qscale, x.y * qscale);
        t.u.y = f2b_pack(x.z * qscale, x.w * qscale);
        t.u.z = f2b_pack(y.x * qscale, y.y * qscale);
        t.u.w = f2b_pack(y.z * qscale, y.w * qscale);
        qf[mi][ks] = t.v;
      }
    }
  }

  f32x4 oacc[2][8];
#pragma unroll
  for (int mi = 0; mi < 2; ++mi)
#pragma unroll
    for (int ni = 0; ni < 8; ++ni) oacc[mi][ni] = (f32x4)0.0f;
  float lacc[2][4] = {};

  const float* kbase = k + ((size_t)b * SKV_ + kv0) * H_ * D_ + (size_t)h * D_;
  const float* vbase = v + ((size_t)b * SKV_ + kv0) * H_ * D_ + (size_t)h * D_;

  for (int t = 0; t < nt; ++t) {
    // ---- stage K tile [KT][128] fp32 -> bf16 LDS (row-major, swizzled)
    const float* kt = kbase + (size_t)t * KT * H_ * D_;
#pragma unroll
    for (int it = 0; it < 8; ++it) {
      int f = it * 256 + tid;
      int key = f >> 5;
      int d4 = (f & 31) * 4;
      float4 x = *(const float4*)(kt + (size_t)key * (H_ * D_) + d4);
      unsigned lo = f2b_pack(x.x, x.y), hi = f2b_pack(x.z, x.w);
      int off = key * 256 + ((d4 * 2) ^ ((key & 7) << 4));
      *(uint2*)(Klds + off) = make_uint2(lo, hi);
    }
    // ---- stage V tile transposed: V_t[d][key] (pairs of keys packed per b32 write)
    const float* vt = vbase + (size_t)t * KT * H_ * D_;
#pragma unroll
    for (int it = 0; it < 4; ++it) {
      int f = it * 256 + tid;
      int kp = f >> 5;                // key pair index 0..31
      int d4 = (f & 31) * 4;
      const float* va = vt + (size_t)(kp * 2) * (H_ * D_) + d4;
      const float* vb = va + H_ * D_;
      float4 xa = *(const float4*)va;
      float4 xb = *(const float4*)vb;
      float aarr[4] = {xa.x, xa.y, xa.z, xa.w};
      float barr[4] = {xb.x, xb.y, xb.z, xb.w};
#pragma unroll
      for (int i = 0; i < 4; ++i) {
        int d = d4 + i;
        unsigned pk = f2b_pack(aarr[i], barr[i]);
        int off = d * 128 + ((kp * 4) ^ (((d ^ (d >> 2)) & 7) << 4));
        *(unsigned*)(Vlds + off) = pk;
      }
    }
    __syncthreads();   // (A) tile staged

    __builtin_amdgcn_s_setprio(1);
    // ---- S = Q K^T  (per wave: 32 rows x 64 keys)
    f32x4 sacc[2][4];
#pragma unroll
    for (int mi = 0; mi < 2; ++mi)
#pragma unroll
      for (int ni = 0; ni < 4; ++ni) sacc[mi][ni] = (f32x4)0.0f;

#pragma unroll
    for (int ni = 0; ni < 4; ++ni) {
      int key = ni * 16 + c;
      int rb = key * 256;
      int sw = (key & 7) << 4;
#pragma unroll
      for (int ks = 0; ks < 4; ++ks) {
        U4B8 bf;
        bf.u = *(uint4*)(Klds + rb + ((ks * 64 + g * 16) ^ sw));
        sacc[0][ni] = __builtin_amdgcn_mfma_f32_16x16x32_bf16(qf[0][ks], bf.v, sacc[0][ni], 0, 0, 0);
        sacc[1][ni] = __builtin_amdgcn_mfma_f32_16x16x32_bf16(qf[1][ks], bf.v, sacc[1][ni], 0, 0, 0);
      }
    }
    __builtin_amdgcn_s_setprio(0);
    __syncthreads();   // (B) all K reads done -> safe to overwrite K region with P

    __builtin_amdgcn_s_setprio(1);
    // ---- p = exp2(s), accumulate row-sum partials, write P (bf16) into overlay
#pragma unroll
    for (int mi = 0; mi < 2; ++mi) {
#pragma unroll
      for (int ni = 0; ni < 4; ++ni) {
#pragma unroll
        for (int r = 0; r < 4; ++r) {
          float p = exp2f(sacc[mi][ni][r]);
          lacc[mi][r] += p;
          int row = mi * 16 + g * 4 + r;
          int col = ni * 16 + c;
          int off = row * 128 + ((col * 2) ^ ((row & 7) << 4));
          *(unsigned short*)(Plds + off) = f2b1(p);
        }
      }
    }

    // ---- O += P V  (A from P overlay, B from V_t LDS; in-wave DS ordering)
#pragma unroll
    for (int ks2 = 0; ks2 < 2; ++ks2) {
      U4B8 ap[2];
#pragma unroll
      for (int mi = 0; mi < 2; ++mi) {
        int row = mi * 16 + c;
        ap[mi].u = *(uint4*)(Plds + row * 128 + ((ks2 * 64 + g * 16) ^ ((row & 7) << 4)));
      }
#pragma unroll
      for (int ni = 0; ni < 8; ++ni) {
        int d = ni * 16 + c;
        U4B8 bv;
        bv.u = *(uint4*)(Vlds + d * 128 + ((ks2 * 64 + g * 16) ^ (((d ^ (d >> 2)) & 7) << 4)));
        oacc[0][ni] = __builtin_amdgcn_mfma_f32_16x16x32_bf16(ap[0].v, bv.v, oacc[0][ni], 0, 0, 0);
        oacc[1][ni] = __builtin_amdgcn_mfma_f32_16x16x32_bf16(ap[1].v, bv.v, oacc[1][ni], 0, 0, 0);
      }
    }
    __builtin_amdgcn_s_setprio(0);
    __syncthreads();   // (C) P & V consumed -> next tile may restage
  }

  // ---- reduce l across the 16 lanes that share each row
#pragma unroll
  for (int mi = 0; mi < 2; ++mi) {
#pragma unroll
    for (int r = 0; r < 4; ++r) {
      float s = lacc[mi][r];
      s += __shfl_xor(s, 1, 16);
      s += __shfl_xor(s, 2, 16);
      s += __shfl_xor(s, 4, 16);
      s += __shfl_xor(s, 8, 16);
      lacc[mi][r] = s;
    }
  }

  if (nsplit == 1) {
    float* op = outp + (((size_t)b * SQ_) * H_ + h) * D_;
#pragma unroll
    for (int mi = 0; mi < 2; ++mi) {
#pragma unroll
      for (int r = 0; r < 4; ++r) {
        int row = w * 32 + mi * 16 + g * 4 + r;
        float inv = 1.0f / lacc[mi][r];
#pragma unroll
        for (int ni = 0; ni < 8; ++ni) {
          op[(size_t)row * (H_ * D_) + ni * 16 + c] = oacc[mi][ni][r] * inv;
        }
      }
    }
  } else {
    float* Up = Ubase + ((size_t)split * 128 + bh) * (SQ_ * D_);
#pragma unroll
    for (int mi = 0; mi < 2; ++mi) {
#pragma unroll
      for (int r = 0; r < 4; ++r) {
        int row = w * 32 + mi * 16 + g * 4 + r;
#pragma unroll
        for (int ni = 0; ni < 8; ++ni) {
          Up[(size_t)row * D_ + ni * 16 + c] = oacc[mi][ni][r];
        }
        if (c == 0) Lbase[((size_t)split * 128 + bh) * SQ_ + row] = lacc[mi][r];
      }
    }
  }
}

// Combine kernel: out = sum_s U_s / sum_s l_s, with layout change [b,h,q,d] -> [b,q,h,d]
__global__ void mha_combine_kernel(const float* __restrict__ Ubase, const float* __restrict__ Lbase,
                                   float* __restrict__ outp, int nsplit) {
  int idx = blockIdx.x * 256 + threadIdx.x;   // over BH*SQ*D = 2M
  int rowlin = idx >> 7;                       // bh*128 + row
  int d = idx & 127;
  float su = 0.f, sl = 0.f;
  for (int s = 0; s < nsplit; ++s) {
    su += Ubase[(size_t)s * (128 * SQ_ * D_) + idx];
    sl += Lbase[(size_t)s * (128 * SQ_) + rowlin];
  }
  int bh = rowlin >> 7, row = rowlin & 127;
  int b = bh >> 5, h = bh & 31;
  outp[(((size_t)b * SQ_ + row) * H_ + h) * D_ + d] = su / sl;
}

extern "C" void kernel_launch(void* const* d_in, const int* in_sizes, int n_in,
                              void* d_out, int out_size, void* d_ws, size_t ws_size,
                              hipStream_t stream) {
  const float* q = (const float*)d_in[0];
  const float* k = (const float*)d_in[1];
  const float* v = (const float*)d_in[2];
  float* outp = (float*)d_out;

  const size_t per_split = (size_t)128 * SQ_ * D_ * 4 + (size_t)128 * SQ_ * 4; // U + l per split
  int nsplit = 1;
  if (ws_size >= 8 * per_split) nsplit = 8;       // 1024 blocks -> 4/CU, all resident
  else if (ws_size >= 4 * per_split) nsplit = 4;
  else if (ws_size >= 2 * per_split) nsplit = 2;

  float* Ubase = (float*)d_ws;
  float* Lbase = Ubase + (size_t)nsplit * 128 * SQ_ * D_;

  dim3 grid(128, nsplit);
  mha_split_kernel<<<grid, 256, 0, stream>>>(q, k, v, Ubase, Lbase, outp, nsplit);
  if (nsplit > 1) {
    mha_combine_kernel<<<(128 * SQ_ * D_) / 256, 256, 0, stream>>>(Ubase, Lbase, outp, nsplit);
  }
}

// Round 6
// 374.800 us; speedup vs baseline: 2.2673x; 2.2673x over previous
//
#include <hip/hip_runtime.h>
#include <hip/hip_bf16.h>
#include <cstdint>

#define B_ 4
#define SQ_ 128
#define SKV_ 8192
#define H_ 32
#define D_ 128
#define KT 64

typedef __bf16 bf16x8 __attribute__((ext_vector_type(8)));
typedef float f32x4 __attribute__((ext_vector_type(4)));

union U4B8 { uint4 u; bf16x8 v; };

__device__ inline unsigned f2b_pack(float a, float b){
  unsigned ua = __float_as_uint(a); ua = (ua + 0x7FFFu + ((ua >> 16) & 1u)) >> 16;
  unsigned ub = __float_as_uint(b); ub = (ub + 0x7FFFu + ((ub >> 16) & 1u)) >> 16;
  return (ua & 0xFFFFu) | (ub << 16);
}
__device__ inline unsigned short f2b1(float a){
  unsigned ua = __float_as_uint(a);
  return (unsigned short)((ua + 0x7FFFu + ((ua >> 16) & 1u)) >> 16);
}

// Split-KV attention. Block = 256 threads = 4 waves; each wave owns 32 Q rows.
// LDS = 32 KB (P overlaid on K region after a barrier). launch_bounds(256,2)
// so the allocator settles at ~124 VGPR (proven in R1-R3) -- NOT (256,4),
// which clamps to 64 VGPR and spills 900 MB (R5). Occupancy comes from actual
// resources: 124 VGPR -> 4 waves/SIMD, 32 KB LDS -> 4 blocks/CU, grid 1024 =
// exactly resident in one scheduling wave.
__global__ __launch_bounds__(256, 2) void mha_split_kernel(
    const float* __restrict__ q, const float* __restrict__ k, const float* __restrict__ v,
    float* __restrict__ Ubase, float* __restrict__ Lbase, float* __restrict__ outp, int nsplit)
{
  __shared__ char smem[32 * 1024] __attribute__((aligned(16)));
  char* Klds = smem;                 // [64][128] bf16, row 256B, swz ^((key&7)<<4)
  char* Vlds = smem + 16 * 1024;     // V^T [128][64] bf16, row 128B, swz ^(((d^(d>>2))&7)<<4)
  char* Plds = smem + (threadIdx.x >> 6) * 4096; // per-wave [32][64] bf16 OVERLAID on K region

  const int tid = threadIdx.x;
  const int w = tid >> 6;
  const int l = tid & 63;
  const int g = l >> 4;      // 16-lane group 0..3
  const int c = l & 15;      // lane within group
  const int bh = blockIdx.x;
  const int split = blockIdx.y;
  const int b = bh >> 5, h = bh & 31;
  const int kps = SKV_ / nsplit;
  const int kv0 = split * kps;
  const int nt = kps / KT;

  const float qscale = 0.08838834764831845f * 1.4426950408889634f; // 1/sqrt(128) * log2(e)

  // ---- Q fragments in registers (A-operand layout: m = c, k = ks*32 + g*8 + j)
  bf16x8 qf[2][4];
  {
    const float* qp = q + (((size_t)b * SQ_) * H_ + h) * D_;
#pragma unroll
    for (int mi = 0; mi < 2; ++mi) {
      int qrow = w * 32 + mi * 16 + c;
      const float* qr = qp + (size_t)qrow * H_ * D_;
#pragma unroll
      for (int ks = 0; ks < 4; ++ks) {
        int d0 = ks * 32 + g * 8;
        float4 x = *(const float4*)(qr + d0);
        float4 y = *(const float4*)(qr + d0 + 4);
        U4B8 t;
        t.u.x = f2b_pack(x.x * qscale, x.y * qscale);
        t.u.y = f2b_pack(x.z * qscale, x.w * qscale);
        t.u.z = f2b_pack(y.x * qscale, y.y * qscale);
        t.u.w = f2b_pack(y.z * qscale, y.w * qscale);
        qf[mi][ks] = t.v;
      }
    }
  }

  f32x4 oacc[2][8];
#pragma unroll
  for (int mi = 0; mi < 2; ++mi)
#pragma unroll
    for (int ni = 0; ni < 8; ++ni) oacc[mi][ni] = (f32x4)0.0f;
  float lacc[2][4] = {};

  const float* kbase = k + ((size_t)b * SKV_ + kv0) * H_ * D_ + (size_t)h * D_;
  const float* vbase = v + ((size_t)b * SKV_ + kv0) * H_ * D_ + (size_t)h * D_;

  for (int t = 0; t < nt; ++t) {
    // ---- stage K tile [KT][128] fp32 -> bf16 LDS (row-major, swizzled)
    const float* kt = kbase + (size_t)t * KT * H_ * D_;
#pragma unroll
    for (int it = 0; it < 8; ++it) {
      int f = it * 256 + tid;
      int key = f >> 5;
      int d4 = (f & 31) * 4;
      float4 x = *(const float4*)(kt + (size_t)key * (H_ * D_) + d4);
      unsigned lo = f2b_pack(x.x, x.y), hi = f2b_pack(x.z, x.w);
      int off = key * 256 + ((d4 * 2) ^ ((key & 7) << 4));
      *(uint2*)(Klds + off) = make_uint2(lo, hi);
    }
    // ---- stage V tile transposed: V_t[d][key] (pairs of keys packed per b32 write)
    const float* vt = vbase + (size_t)t * KT * H_ * D_;
#pragma unroll
    for (int it = 0; it < 4; ++it) {
      int f = it * 256 + tid;
      int kp = f >> 5;                // key pair index 0..31
      int d4 = (f & 31) * 4;
      const float* va = vt + (size_t)(kp * 2) * (H_ * D_) + d4;
      const float* vb = va + H_ * D_;
      float4 xa = *(const float4*)va;
      float4 xb = *(const float4*)vb;
      float aarr[4] = {xa.x, xa.y, xa.z, xa.w};
      float barr[4] = {xb.x, xb.y, xb.z, xb.w};
#pragma unroll
      for (int i = 0; i < 4; ++i) {
        int d = d4 + i;
        unsigned pk = f2b_pack(aarr[i], barr[i]);
        int off = d * 128 + ((kp * 4) ^ (((d ^ (d >> 2)) & 7) << 4));
        *(unsigned*)(Vlds + off) = pk;
      }
    }
    __syncthreads();   // (A) tile staged

    __builtin_amdgcn_s_setprio(1);
    // ---- S = Q K^T  (per wave: 32 rows x 64 keys)
    f32x4 sacc[2][4];
#pragma unroll
    for (int mi = 0; mi < 2; ++mi)
#pragma unroll
      for (int ni = 0; ni < 4; ++ni) sacc[mi][ni] = (f32x4)0.0f;

#pragma unroll
    for (int ni = 0; ni < 4; ++ni) {
      int key = ni * 16 + c;
      int rb = key * 256;
      int sw = (key & 7) << 4;
#pragma unroll
      for (int ks = 0; ks < 4; ++ks) {
        U4B8 bf;
        bf.u = *(uint4*)(Klds + rb + ((ks * 64 + g * 16) ^ sw));
        sacc[0][ni] = __builtin_amdgcn_mfma_f32_16x16x32_bf16(qf[0][ks], bf.v, sacc[0][ni], 0, 0, 0);
        sacc[1][ni] = __builtin_amdgcn_mfma_f32_16x16x32_bf16(qf[1][ks], bf.v, sacc[1][ni], 0, 0, 0);
      }
    }
    __builtin_amdgcn_s_setprio(0);
    __syncthreads();   // (B) all K reads done -> safe to overwrite K region with P

    __builtin_amdgcn_s_setprio(1);
    // ---- p = exp2(s), accumulate row-sum partials, write P (bf16) into overlay
#pragma unroll
    for (int mi = 0; mi < 2; ++mi) {
#pragma unroll
      for (int ni = 0; ni < 4; ++ni) {
#pragma unroll
        for (int r = 0; r < 4; ++r) {
          float p = exp2f(sacc[mi][ni][r]);
          lacc[mi][r] += p;
          int row = mi * 16 + g * 4 + r;
          int col = ni * 16 + c;
          int off = row * 128 + ((col * 2) ^ ((row & 7) << 4));
          *(unsigned short*)(Plds + off) = f2b1(p);
        }
      }
    }

    // ---- O += P V  (A from P overlay, B from V_t LDS; in-wave DS ordering)
#pragma unroll
    for (int ks2 = 0; ks2 < 2; ++ks2) {
      U4B8 ap[2];
#pragma unroll
      for (int mi = 0; mi < 2; ++mi) {
        int row = mi * 16 + c;
        ap[mi].u = *(uint4*)(Plds + row * 128 + ((ks2 * 64 + g * 16) ^ ((row & 7) << 4)));
      }
#pragma unroll
      for (int ni = 0; ni < 8; ++ni) {
        int d = ni * 16 + c;
        U4B8 bv;
        bv.u = *(uint4*)(Vlds + d * 128 + ((ks2 * 64 + g * 16) ^ (((d ^ (d >> 2)) & 7) << 4)));
        oacc[0][ni] = __builtin_amdgcn_mfma_f32_16x16x32_bf16(ap[0].v, bv.v, oacc[0][ni], 0, 0, 0);
        oacc[1][ni] = __builtin_amdgcn_mfma_f32_16x16x32_bf16(ap[1].v, bv.v, oacc[1][ni], 0, 0, 0);
      }
    }
    __builtin_amdgcn_s_setprio(0);
    __syncthreads();   // (C) P & V consumed -> next tile may restage
  }

  // ---- reduce l across the 16 lanes that share each row
#pragma unroll
  for (int mi = 0; mi < 2; ++mi) {
#pragma unroll
    for (int r = 0; r < 4; ++r) {
      float s = lacc[mi][r];
      s += __shfl_xor(s, 1, 16);
      s += __shfl_xor(s, 2, 16);
      s += __shfl_xor(s, 4, 16);
      s += __shfl_xor(s, 8, 16);
      lacc[mi][r] = s;
    }
  }

  if (nsplit == 1) {
    float* op = outp + (((size_t)b * SQ_) * H_ + h) * D_;
#pragma unroll
    for (int mi = 0; mi < 2; ++mi) {
#pragma unroll
      for (int r = 0; r < 4; ++r) {
        int row = w * 32 + mi * 16 + g * 4 + r;
        float inv = 1.0f / lacc[mi][r];
#pragma unroll
        for (int ni = 0; ni < 8; ++ni) {
          op[(size_t)row * (H_ * D_) + ni * 16 + c] = oacc[mi][ni][r] * inv;
        }
      }
    }
  } else {
    float* Up = Ubase + ((size_t)split * 128 + bh) * (SQ_ * D_);
#pragma unroll
    for (int mi = 0; mi < 2; ++mi) {
#pragma unroll
      for (int r = 0; r < 4; ++r) {
        int row = w * 32 + mi * 16 + g * 4 + r;
#pragma unroll
        for (int ni = 0; ni < 8; ++ni) {
          Up[(size_t)row * D_ + ni * 16 + c] = oacc[mi][ni][r];
        }
        if (c == 0) Lbase[((size_t)split * 128 + bh) * SQ_ + row] = lacc[mi][r];
      }
    }
  }
}

// Combine kernel: out = sum_s U_s / sum_s l_s, with layout change [b,h,q,d] -> [b,q,h,d]
__global__ void mha_combine_kernel(const float* __restrict__ Ubase, const float* __restrict__ Lbase,
                                   float* __restrict__ outp, int nsplit) {
  int idx = blockIdx.x * 256 + threadIdx.x;   // over BH*SQ*D = 2M
  int rowlin = idx >> 7;                       // bh*128 + row
  int d = idx & 127;
  float su = 0.f, sl = 0.f;
  for (int s = 0; s < nsplit; ++s) {
    su += Ubase[(size_t)s * (128 * SQ_ * D_) + idx];
    sl += Lbase[(size_t)s * (128 * SQ_) + rowlin];
  }
  int bh = rowlin >> 7, row = rowlin & 127;
  int b = bh >> 5, h = bh & 31;
  outp[(((size_t)b * SQ_ + row) * H_ + h) * D_ + d] = su / sl;
}

extern "C" void kernel_launch(void* const* d_in, const int* in_sizes, int n_in,
                              void* d_out, int out_size, void* d_ws, size_t ws_size,
                              hipStream_t stream) {
  const float* q = (const float*)d_in[0];
  const float* k = (const float*)d_in[1];
  const float* v = (const float*)d_in[2];
  float* outp = (float*)d_out;

  const size_t per_split = (size_t)128 * SQ_ * D_ * 4 + (size_t)128 * SQ_ * 4; // U + l per split
  int nsplit = 1;
  if (ws_size >= 8 * per_split) nsplit = 8;       // 1024 blocks -> 4/CU, all resident
  else if (ws_size >= 4 * per_split) nsplit = 4;
  else if (ws_size >= 2 * per_split) nsplit = 2;

  float* Ubase = (float*)d_ws;
  float* Lbase = Ubase + (size_t)nsplit * 128 * SQ_ * D_;

  dim3 grid(128, nsplit);
  mha_split_kernel<<<grid, 256, 0, stream>>>(q, k, v, Ubase, Lbase, outp, nsplit);
  if (nsplit > 1) {
    mha_combine_kernel<<<(128 * SQ_ * D_) / 256, 256, 0, stream>>>(Ubase, Lbase, outp, nsplit);
  }
}

// Round 7
// 254.630 us; speedup vs baseline: 3.3373x; 1.4719x over previous
//
#include <hip/hip_runtime.h>
#include <hip/hip_bf16.h>
#include <cstdint>

#define B_ 4
#define SQ_ 128
#define SKV_ 8192
#define H_ 32
#define D_ 128
#define KT 64

typedef __bf16 bf16x8 __attribute__((ext_vector_type(8)));
typedef float f32x4 __attribute__((ext_vector_type(4)));

union U4B8 { uint4 u; bf16x8 v; };

__device__ inline unsigned f2b_pack(float a, float b){
  unsigned ua = __float_as_uint(a); ua = (ua + 0x7FFFu + ((ua >> 16) & 1u)) >> 16;
  unsigned ub = __float_as_uint(b); ub = (ub + 0x7FFFu + ((ub >> 16) & 1u)) >> 16;
  return (ua & 0xFFFFu) | (ub << 16);
}
__device__ inline unsigned short f2b1(float a){
  unsigned ua = __float_as_uint(a);
  return (unsigned short)((ua + 0x7FFFu + ((ua >> 16) & 1u)) >> 16);
}

// Split-KV attention. Block = 512 threads = 8 waves; each wave owns 16 Q rows
// (register diet: R6 showed 124 arch VGPR + 64 AGPR = 188/wave -> 2 waves/SIMD.
// Halving the per-wave Q tile cuts qf+sacc+oacc from 128 to 64 regs ->
// ~110 total -> 4 waves/SIMD). LDS 32 KB: K 16KB + V^T 16KB, per-wave P (2KB)
// overlaid on K after barrier (B). 2 blocks/CU x 8 waves = 16 waves/CU.
// Grid = (128, 4) = 512 blocks = exactly resident in one scheduling wave.
__global__ __launch_bounds__(512, 2) void mha_split_kernel(
    const float* __restrict__ q, const float* __restrict__ k, const float* __restrict__ v,
    float* __restrict__ Ubase, float* __restrict__ Lbase, float* __restrict__ outp, int nsplit)
{
  __shared__ char smem[32 * 1024] __attribute__((aligned(16)));
  char* Klds = smem;                 // [64][128] bf16, row 256B, swz ^((key&7)<<4)
  char* Vlds = smem + 16 * 1024;     // V^T [128][64] bf16, row 128B, swz ^(((d^(d>>2))&7)<<4)
  char* Plds = smem + (threadIdx.x >> 6) * 2048; // per-wave [16][64] bf16 OVERLAID on K region

  const int tid = threadIdx.x;
  const int w = tid >> 6;
  const int l = tid & 63;
  const int g = l >> 4;      // 16-lane group 0..3
  const int c = l & 15;      // lane within group
  const int bh = blockIdx.x;
  const int split = blockIdx.y;
  const int b = bh >> 5, h = bh & 31;
  const int kps = SKV_ / nsplit;
  const int kv0 = split * kps;
  const int nt = kps / KT;

  const float qscale = 0.08838834764831845f * 1.4426950408889634f; // 1/sqrt(128) * log2(e)

  // ---- Q fragments in registers (A-operand layout: m = c, k = ks*32 + g*8 + j)
  bf16x8 qf[4];
  {
    const float* qp = q + (((size_t)b * SQ_) * H_ + h) * D_;
    int qrow = w * 16 + c;
    const float* qr = qp + (size_t)qrow * H_ * D_;
#pragma unroll
    for (int ks = 0; ks < 4; ++ks) {
      int d0 = ks * 32 + g * 8;
      float4 x = *(const float4*)(qr + d0);
      float4 y = *(const float4*)(qr + d0 + 4);
      U4B8 t;
      t.u.x = f2b_pack(x.x * qscale, x.y * qscale);
      t.u.y = f2b_pack(x.z * qscale, x.w * qscale);
      t.u.z = f2b_pack(y.x * qscale, y.y * qscale);
      t.u.w = f2b_pack(y.z * qscale, y.w * qscale);
      qf[ks] = t.v;
    }
  }

  f32x4 oacc[8];
#pragma unroll
  for (int ni = 0; ni < 8; ++ni) oacc[ni] = (f32x4)0.0f;
  float lacc[4] = {};

  const float* kbase = k + ((size_t)b * SKV_ + kv0) * H_ * D_ + (size_t)h * D_;
  const float* vbase = v + ((size_t)b * SKV_ + kv0) * H_ * D_ + (size_t)h * D_;

  for (int t = 0; t < nt; ++t) {
    // ---- stage K tile [KT][128] fp32 -> bf16 LDS (row-major, swizzled); 512 threads
    const float* kt = kbase + (size_t)t * KT * H_ * D_;
#pragma unroll
    for (int it = 0; it < 4; ++it) {
      int f = it * 512 + tid;
      int key = f >> 5;
      int d4 = (f & 31) * 4;
      float4 x = *(const float4*)(kt + (size_t)key * (H_ * D_) + d4);
      unsigned lo = f2b_pack(x.x, x.y), hi = f2b_pack(x.z, x.w);
      int off = key * 256 + ((d4 * 2) ^ ((key & 7) << 4));
      *(uint2*)(Klds + off) = make_uint2(lo, hi);
    }
    // ---- stage V tile transposed: V_t[d][key] (pairs of keys packed per b32 write)
    const float* vt = vbase + (size_t)t * KT * H_ * D_;
#pragma unroll
    for (int it = 0; it < 2; ++it) {
      int f = it * 512 + tid;
      int kp = f >> 5;                // key pair index 0..31
      int d4 = (f & 31) * 4;
      const float* va = vt + (size_t)(kp * 2) * (H_ * D_) + d4;
      const float* vb = va + H_ * D_;
      float4 xa = *(const float4*)va;
      float4 xb = *(const float4*)vb;
      float aarr[4] = {xa.x, xa.y, xa.z, xa.w};
      float barr[4] = {xb.x, xb.y, xb.z, xb.w};
#pragma unroll
      for (int i = 0; i < 4; ++i) {
        int d = d4 + i;
        unsigned pk = f2b_pack(aarr[i], barr[i]);
        int off = d * 128 + ((kp * 4) ^ (((d ^ (d >> 2)) & 7) << 4));
        *(unsigned*)(Vlds + off) = pk;
      }
    }
    __syncthreads();   // (A) tile staged

    __builtin_amdgcn_s_setprio(1);
    // ---- S = Q K^T  (per wave: 16 rows x 64 keys)
    f32x4 sacc[4];
#pragma unroll
    for (int ni = 0; ni < 4; ++ni) sacc[ni] = (f32x4)0.0f;

#pragma unroll
    for (int ni = 0; ni < 4; ++ni) {
      int key = ni * 16 + c;
      int rb = key * 256;
      int sw = (key & 7) << 4;
#pragma unroll
      for (int ks = 0; ks < 4; ++ks) {
        U4B8 bf;
        bf.u = *(uint4*)(Klds + rb + ((ks * 64 + g * 16) ^ sw));
        sacc[ni] = __builtin_amdgcn_mfma_f32_16x16x32_bf16(qf[ks], bf.v, sacc[ni], 0, 0, 0);
      }
    }
    __builtin_amdgcn_s_setprio(0);
    __syncthreads();   // (B) all K reads done -> safe to overwrite K region with P

    __builtin_amdgcn_s_setprio(1);
    // ---- p = exp2(s), accumulate row-sum partials, write P (bf16) into overlay
#pragma unroll
    for (int ni = 0; ni < 4; ++ni) {
#pragma unroll
      for (int r = 0; r < 4; ++r) {
        float p = exp2f(sacc[ni][r]);
        lacc[r] += p;
        int row = g * 4 + r;
        int col = ni * 16 + c;
        int off = row * 128 + ((col * 2) ^ ((row & 7) << 4));
        *(unsigned short*)(Plds + off) = f2b1(p);
      }
    }

    // ---- O += P V  (A from P overlay, B from V_t LDS; in-wave DS ordering)
#pragma unroll
    for (int ks2 = 0; ks2 < 2; ++ks2) {
      U4B8 ap;
      {
        int row = c;
        ap.u = *(uint4*)(Plds + row * 128 + ((ks2 * 64 + g * 16) ^ ((row & 7) << 4)));
      }
#pragma unroll
      for (int ni = 0; ni < 8; ++ni) {
        int d = ni * 16 + c;
        U4B8 bv;
        bv.u = *(uint4*)(Vlds + d * 128 + ((ks2 * 64 + g * 16) ^ (((d ^ (d >> 2)) & 7) << 4)));
        oacc[ni] = __builtin_amdgcn_mfma_f32_16x16x32_bf16(ap.v, bv.v, oacc[ni], 0, 0, 0);
      }
    }
    __builtin_amdgcn_s_setprio(0);
    __syncthreads();   // (C) P & V consumed -> next tile may restage
  }

  // ---- reduce l across the 16 lanes that share each row
#pragma unroll
  for (int r = 0; r < 4; ++r) {
    float s = lacc[r];
    s += __shfl_xor(s, 1, 16);
    s += __shfl_xor(s, 2, 16);
    s += __shfl_xor(s, 4, 16);
    s += __shfl_xor(s, 8, 16);
    lacc[r] = s;
  }

  if (nsplit == 1) {
    float* op = outp + (((size_t)b * SQ_) * H_ + h) * D_;
#pragma unroll
    for (int r = 0; r < 4; ++r) {
      int row = w * 16 + g * 4 + r;
      float inv = 1.0f / lacc[r];
#pragma unroll
      for (int ni = 0; ni < 8; ++ni) {
        op[(size_t)row * (H_ * D_) + ni * 16 + c] = oacc[ni][r] * inv;
      }
    }
  } else {
    float* Up = Ubase + ((size_t)split * 128 + bh) * (SQ_ * D_);
#pragma unroll
    for (int r = 0; r < 4; ++r) {
      int row = w * 16 + g * 4 + r;
#pragma unroll
      for (int ni = 0; ni < 8; ++ni) {
        Up[(size_t)row * D_ + ni * 16 + c] = oacc[ni][r];
      }
      if (c == 0) Lbase[((size_t)split * 128 + bh) * SQ_ + row] = lacc[r];
    }
  }
}

// Combine kernel: out = sum_s U_s / sum_s l_s, with layout change [b,h,q,d] -> [b,q,h,d]
__global__ void mha_combine_kernel(const float* __restrict__ Ubase, const float* __restrict__ Lbase,
                                   float* __restrict__ outp, int nsplit) {
  int idx = blockIdx.x * 256 + threadIdx.x;   // over BH*SQ*D = 2M
  int rowlin = idx >> 7;                       // bh*128 + row
  int d = idx & 127;
  float su = 0.f, sl = 0.f;
  for (int s = 0; s < nsplit; ++s) {
    su += Ubase[(size_t)s * (128 * SQ_ * D_) + idx];
    sl += Lbase[(size_t)s * (128 * SQ_) + rowlin];
  }
  int bh = rowlin >> 7, row = rowlin & 127;
  int b = bh >> 5, h = bh & 31;
  outp[(((size_t)b * SQ_ + row) * H_ + h) * D_ + d] = su / sl;
}

extern "C" void kernel_launch(void* const* d_in, const int* in_sizes, int n_in,
                              void* d_out, int out_size, void* d_ws, size_t ws_size,
                              hipStream_t stream) {
  const float* q = (const float*)d_in[0];
  const float* k = (const float*)d_in[1];
  const float* v = (const float*)d_in[2];
  float* outp = (float*)d_out;

  const size_t per_split = (size_t)128 * SQ_ * D_ * 4 + (size_t)128 * SQ_ * 4; // U + l per split
  int nsplit = 1;
  if (ws_size >= 4 * per_split) nsplit = 4;       // 512 blocks of 512 thr = 2/CU, all resident
  else if (ws_size >= 2 * per_split) nsplit = 2;

  float* Ubase = (float*)d_ws;
  float* Lbase = Ubase + (size_t)nsplit * 128 * SQ_ * D_;

  dim3 grid(128, nsplit);
  mha_split_kernel<<<grid, 512, 0, stream>>>(q, k, v, Ubase, Lbase, outp, nsplit);
  if (nsplit > 1) {
    mha_combine_kernel<<<(128 * SQ_ * D_) / 256, 256, 0, stream>>>(Ubase, Lbase, outp, nsplit);
  }
}

// Round 8
// 197.582 us; speedup vs baseline: 4.3009x; 1.2887x over previous
//
#include <hip/hip_runtime.h>
#include <hip/hip_bf16.h>
#include <cstdint>

#define B_ 4
#define SQ_ 128
#define SKV_ 8192
#define H_ 32
#define D_ 128
#define KT 32
#define HD (H_ * D_)

typedef __bf16 bf16x8 __attribute__((ext_vector_type(8)));
typedef float f32x4 __attribute__((ext_vector_type(4)));

union U4B8 { uint4 u; bf16x8 v; };

__device__ inline unsigned f2b_pack(float a, float b){
  unsigned ua = __float_as_uint(a); ua = (ua + 0x7FFFu + ((ua >> 16) & 1u)) >> 16;
  unsigned ub = __float_as_uint(b); ub = (ub + 0x7FFFu + ((ub >> 16) & 1u)) >> 16;
  return (ua & 0xFFFFu) | (ub << 16);
}
__device__ inline unsigned short f2b1(float a){
  unsigned ua = __float_as_uint(a);
  return (unsigned short)((ua + 0x7FFFu + ((ua >> 16) & 1u)) >> 16);
}

// Split-KV attention, register-carried double-buffer pipeline.
// Block = 512 threads = 8 waves; each wave owns 16 Q rows. KT=32 keys/tile.
// Per iter t: issue global loads for tile t+1 (16 VGPRs, pinned by
// sched_barrier) -> compute tile t from LDS buf[cur] -> convert+write regs to
// buf[cur^1] (vmcnt wait lands here, covered by compute) -> ONE barrier.
// P is a dedicated per-wave LDS region: in-wave ds ordering makes write->read
// safe without a barrier. LDS: K dbuf 16K + V dbuf 16K + P 8K = 40 KB.
// launch_bounds(512,4): cap 128 regs total -> 2 blocks x 8 waves = 16 waves/CU.
__global__ __launch_bounds__(512, 4) void mha_split_kernel(
    const float* __restrict__ q, const float* __restrict__ k, const float* __restrict__ v,
    float* __restrict__ Ubase, float* __restrict__ Lbase, float* __restrict__ outp, int nsplit)
{
  __shared__ char smem[40 * 1024] __attribute__((aligned(16)));
  // K0 @0, K1 @8K: [32 keys][128 d] bf16, 256B rows, slot swz ^((key&7)<<4)
  // V0 @16K, V1 @24K: V^T [128 d][32 keys] bf16, 64B rows, slot swz ^((d>>2)&3)
  // P  @32K: per-wave [16 rows][32 cols] bf16, 64B rows, slot swz ^((row>>2)&3)

  const int tid = threadIdx.x;
  const int w = tid >> 6;
  const int l = tid & 63;
  const int g = l >> 4;      // 16-lane group 0..3
  const int c = l & 15;      // lane within group
  char* Plds = smem + 32768 + w * 1024;

  const int bh = blockIdx.x;
  const int split = blockIdx.y;
  const int b = bh >> 5, h = bh & 31;
  const int kps = SKV_ / nsplit;
  const int kv0 = split * kps;
  const int nt = kps / KT;

  const float qscale = 0.08838834764831845f * 1.4426950408889634f; // 1/sqrt(128)*log2(e)

  // ---- Q fragments (A-operand: m=c, k = ks*32 + g*8 + j); wave rows w*16..w*16+15
  bf16x8 qf[4];
  {
    const float* qr = q + (((size_t)b * SQ_ + (w * 16 + c)) * H_ + h) * D_;
#pragma unroll
    for (int ks = 0; ks < 4; ++ks) {
      int d0 = ks * 32 + g * 8;
      float4 x = *(const float4*)(qr + d0);
      float4 y = *(const float4*)(qr + d0 + 4);
      U4B8 t;
      t.u.x = f2b_pack(x.x * qscale, x.y * qscale);
      t.u.y = f2b_pack(x.z * qscale, x.w * qscale);
      t.u.z = f2b_pack(y.x * qscale, y.y * qscale);
      t.u.w = f2b_pack(y.z * qscale, y.w * qscale);
      qf[ks] = t.v;
    }
  }

  f32x4 oacc[8];
#pragma unroll
  for (int ni = 0; ni < 8; ++ni) oacc[ni] = (f32x4)0.0f;
  float lacc[4] = {};

  const float* kbase = k + ((size_t)b * SKV_ + kv0) * HD + (size_t)h * D_;
  const float* vbase = v + ((size_t)b * SKV_ + kv0) * HD + (size_t)h * D_;

  // staging assignments (512 threads, 32-key tile)
  const int key_s = tid >> 4;          // 0..31  (K: one key row, 8 floats)
  const int d8_s  = (tid & 15) * 8;    // K: d offset
  const int kp_s  = tid >> 5;          // 0..15  (V: key pair, 4 d-values x 2 keys)
  const int d4_s  = (tid & 31) * 4;    // V: d offset
  const int koff_w = key_s * 256 + ((d8_s * 2) ^ ((key_s & 7) << 4));

  float4 kreg0, kreg1, vreg0, vreg1;

  // ---- prologue: stage tile 0 into buf 0
  {
    const float* kt = kbase + (size_t)key_s * HD + d8_s;
    kreg0 = *(const float4*)(kt);
    kreg1 = *(const float4*)(kt + 4);
    const float* vt = vbase + (size_t)(kp_s * 2) * HD + d4_s;
    vreg0 = *(const float4*)(vt);
    vreg1 = *(const float4*)(vt + HD);
    uint4 kw;
    kw.x = f2b_pack(kreg0.x, kreg0.y); kw.y = f2b_pack(kreg0.z, kreg0.w);
    kw.z = f2b_pack(kreg1.x, kreg1.y); kw.w = f2b_pack(kreg1.z, kreg1.w);
    *(uint4*)(smem + koff_w) = kw;
    float va[4] = {vreg0.x, vreg0.y, vreg0.z, vreg0.w};
    float vb[4] = {vreg1.x, vreg1.y, vreg1.z, vreg1.w};
#pragma unroll
    for (int i = 0; i < 4; ++i) {
      int d = d4_s + i;
      int slot = ((kp_s >> 2) ^ ((d >> 2) & 3)) & 3;
      *(unsigned*)(smem + 16384 + d * 64 + slot * 16 + (kp_s & 3) * 4) = f2b_pack(va[i], vb[i]);
    }
  }
  __syncthreads();

  for (int t = 0; t < nt; ++t) {
    const int cur = t & 1;
    char* kc = smem + cur * 8192;
    char* vc = smem + 16384 + cur * 8192;

    // ---- issue prefetch loads for tile t+1 (held in regs through compute)
    if (t + 1 < nt) {
      const float* kt = kbase + (size_t)(t + 1) * KT * HD + (size_t)key_s * HD + d8_s;
      kreg0 = *(const float4*)(kt);
      kreg1 = *(const float4*)(kt + 4);
      const float* vt = vbase + (size_t)(t + 1) * KT * HD + (size_t)(kp_s * 2) * HD + d4_s;
      vreg0 = *(const float4*)(vt);
      vreg1 = *(const float4*)(vt + HD);
    }
    __builtin_amdgcn_sched_barrier(0);  // pin loads above the compute

    __builtin_amdgcn_s_setprio(1);
    // ---- S = Q K^T (16 rows x 32 keys: 8 MFMA)
    f32x4 sacc[2];
#pragma unroll
    for (int ni = 0; ni < 2; ++ni) sacc[ni] = (f32x4)0.0f;
#pragma unroll
    for (int ni = 0; ni < 2; ++ni) {
      int key = ni * 16 + c;
      int rb = key * 256;
      int sw = (key & 7) << 4;
#pragma unroll
      for (int ks = 0; ks < 4; ++ks) {
        U4B8 bf;
        bf.u = *(uint4*)(kc + rb + ((ks * 64 + g * 16) ^ sw));
        sacc[ni] = __builtin_amdgcn_mfma_f32_16x16x32_bf16(qf[ks], bf.v, sacc[ni], 0, 0, 0);
      }
    }

    // ---- p = exp2(s) -> P (wave-private; in-wave lgkm ordering, no barrier)
#pragma unroll
    for (int ni = 0; ni < 2; ++ni) {
#pragma unroll
      for (int r = 0; r < 4; ++r) {
        float p = exp2f(sacc[ni][r]);
        lacc[r] += p;
        int row = g * 4 + r;
        int col = ni * 16 + c;
        int off = row * 64 + ((((col >> 3) ^ g) & 3) * 16) + (col & 7) * 2;
        *(unsigned short*)(Plds + off) = f2b1(p);
      }
    }

    // ---- O += P V (one K=32 step x 8 d-blocks)
    {
      const int slot = ((g ^ (c >> 2)) & 3) * 16;
      U4B8 ap;
      ap.u = *(uint4*)(Plds + c * 64 + slot);
#pragma unroll
      for (int ni = 0; ni < 8; ++ni) {
        int d = ni * 16 + c;
        U4B8 bv;
        bv.u = *(uint4*)(vc + d * 64 + slot);
        oacc[ni] = __builtin_amdgcn_mfma_f32_16x16x32_bf16(ap.v, bv.v, oacc[ni], 0, 0, 0);
      }
    }
    __builtin_amdgcn_s_setprio(0);

    // ---- convert + write prefetched tile into buf[cur^1] (vmcnt wait lands here)
    if (t + 1 < nt) {
      char* kn = smem + (cur ^ 1) * 8192;
      char* vn = smem + 16384 + (cur ^ 1) * 8192;
      uint4 kw;
      kw.x = f2b_pack(kreg0.x, kreg0.y); kw.y = f2b_pack(kreg0.z, kreg0.w);
      kw.z = f2b_pack(kreg1.x, kreg1.y); kw.w = f2b_pack(kreg1.z, kreg1.w);
      *(uint4*)(kn + koff_w) = kw;
      float va[4] = {vreg0.x, vreg0.y, vreg0.z, vreg0.w};
      float vb[4] = {vreg1.x, vreg1.y, vreg1.z, vreg1.w};
#pragma unroll
      for (int i = 0; i < 4; ++i) {
        int d = d4_s + i;
        int slot = ((kp_s >> 2) ^ ((d >> 2) & 3)) & 3;
        *(unsigned*)(vn + d * 64 + slot * 16 + (kp_s & 3) * 4) = f2b_pack(va[i], vb[i]);
      }
    }
    __syncthreads();   // staged writes visible; all reads of buf[cur] done
  }

  // ---- reduce l across the 16 lanes sharing each row
#pragma unroll
  for (int r = 0; r < 4; ++r) {
    float s = lacc[r];
    s += __shfl_xor(s, 1, 16);
    s += __shfl_xor(s, 2, 16);
    s += __shfl_xor(s, 4, 16);
    s += __shfl_xor(s, 8, 16);
    lacc[r] = s;
  }

  if (nsplit == 1) {
    float* op = outp + (((size_t)b * SQ_) * H_ + h) * D_;
#pragma unroll
    for (int r = 0; r < 4; ++r) {
      int row = w * 16 + g * 4 + r;
      float inv = 1.0f / lacc[r];
#pragma unroll
      for (int ni = 0; ni < 8; ++ni) {
        op[(size_t)row * HD + ni * 16 + c] = oacc[ni][r] * inv;
      }
    }
  } else {
    float* Up = Ubase + ((size_t)split * 128 + bh) * (SQ_ * D_);
#pragma unroll
    for (int r = 0; r < 4; ++r) {
      int row = w * 16 + g * 4 + r;
#pragma unroll
      for (int ni = 0; ni < 8; ++ni) {
        Up[(size_t)row * D_ + ni * 16 + c] = oacc[ni][r];
      }
      if (c == 0) Lbase[((size_t)split * 128 + bh) * SQ_ + row] = lacc[r];
    }
  }
}

// Combine kernel: out = sum_s U_s / sum_s l_s, layout [b,h,q,d] -> [b,q,h,d]
__global__ void mha_combine_kernel(const float* __restrict__ Ubase, const float* __restrict__ Lbase,
                                   float* __restrict__ outp, int nsplit) {
  int idx = blockIdx.x * 256 + threadIdx.x;   // over BH*SQ*D = 2M
  int rowlin = idx >> 7;                       // bh*128 + row
  int d = idx & 127;
  float su = 0.f, sl = 0.f;
  for (int s = 0; s < nsplit; ++s) {
    su += Ubase[(size_t)s * (128 * SQ_ * D_) + idx];
    sl += Lbase[(size_t)s * (128 * SQ_) + rowlin];
  }
  int bh = rowlin >> 7, row = rowlin & 127;
  int b = bh >> 5, h = bh & 31;
  outp[(((size_t)b * SQ_ + row) * H_ + h) * D_ + d] = su / sl;
}

extern "C" void kernel_launch(void* const* d_in, const int* in_sizes, int n_in,
                              void* d_out, int out_size, void* d_ws, size_t ws_size,
                              hipStream_t stream) {
  const float* q = (const float*)d_in[0];
  const float* k = (const float*)d_in[1];
  const float* v = (const float*)d_in[2];
  float* outp = (float*)d_out;

  const size_t per_split = (size_t)128 * SQ_ * D_ * 4 + (size_t)128 * SQ_ * 4; // U + l
  int nsplit = 1;
  if (ws_size >= 4 * per_split) nsplit = 4;       // 512 blocks of 512 thr = 2/CU resident
  else if (ws_size >= 2 * per_split) nsplit = 2;

  float* Ubase = (float*)d_ws;
  float* Lbase = Ubase + (size_t)nsplit * 128 * SQ_ * D_;

  dim3 grid(128, nsplit);
  mha_split_kernel<<<grid, 512, 0, stream>>>(q, k, v, Ubase, Lbase, outp, nsplit);
  if (nsplit > 1) {
    mha_combine_kernel<<<(128 * SQ_ * D_) / 256, 256, 0, stream>>>(Ubase, Lbase, outp, nsplit);
  }
}